// Round 17
// baseline (848.170 us; speedup 1.0000x reference)
//
#include <hip/hip_runtime.h>
#include <hip/hip_bf16.h>

using bf16 = __hip_bfloat16;

#define B_      8
#define C_      512
#define H_      56
#define W_      56
#define HW_     3136
#define M_      25088   // B_*HW_
#define NH_     16
#define HD_     32
#define WS_     7
#define NT_     49

typedef __attribute__((ext_vector_type(8))) short bf16x8;
typedef __attribute__((ext_vector_type(4))) float f32x4;

#define AS1(p) ((const __attribute__((address_space(1))) void*)(p))
#define AS3(p) ((__attribute__((address_space(3))) void*)(p))

// ---------- helpers ----------
__device__ inline float bf2f(const bf16 v) {
    unsigned short u = *reinterpret_cast<const unsigned short*>(&v);
    return __uint_as_float((unsigned)u << 16);
}
__device__ inline unsigned short f2bfu(float f) {
    bf16 h = __float2bfloat16(f);
    return *reinterpret_cast<unsigned short*>(&h);
}
__device__ inline float rdv(const float* p) { return *p; }
__device__ inline float rdv(const bf16* p)  { return bf2f(*p); }
__device__ inline void stv(float* p, float v) { *p = v; }
__device__ inline void stv(bf16* p, float v)  { *p = __float2bfloat16(v); }

__device__ inline float gelu_t(float v) {
    const float u = v * (0.79788456080286536f + 0.035677408136300125f * v * v);
    const float e = __expf(2.0f * u);
    return 0.5f * v * (2.0f - 2.0f / (e + 1.0f));
}

// ---------- dtype detector ----------
__global__ void k_detect(const void* g1, int* flag) {
    const unsigned short* u = (const unsigned short*)g1;
    *flag = (u[0] == 0x3F80u) ? 1 : 0;
}

// ---------- fused weight conversion ----------
struct WArgs {
    const void* src[26];
    bf16*       dst[26];
    int         n[26];
};
__global__ __launch_bounds__(256) void k_convert_all(WArgs a, const int* flag) {
    const int isb = *flag;
    const int gid = blockIdx.x * 256 + threadIdx.x;
    const int stride = gridDim.x * 256;
    #pragma unroll 1
    for (int w = 0; w < 26; ++w) {
        const int n = a.n[w];
        bf16* d = a.dst[w];
        if (isb) {
            const unsigned short* s = (const unsigned short*)a.src[w];
            for (int i = gid; i < n; i += stride) ((unsigned short*)d)[i] = s[i];
        } else {
            const float* s = (const float*)a.src[w];
            for (int i = gid; i < n; i += stride) d[i] = __float2bfloat16(s[i]);
        }
    }
}

// ---------- input transpose ----------
__global__ __launch_bounds__(256) void k_transpose_in(const void* xin, bf16* X,
                                                      const int* flag) {
    __shared__ float tile[32][33];
    const int isb = *flag;
    const int p0 = blockIdx.x * 32, c0 = blockIdx.y * 32, b = blockIdx.z;
    const int tp = threadIdx.x & 31, tc = threadIdx.x >> 5;
    const size_t ibase = (size_t)b * C_ * HW_;
    #pragma unroll
    for (int i = 0; i < 4; ++i) {
        const int c = tc + i * 8;
        const size_t idx = ibase + (size_t)(c0 + c) * HW_ + p0 + tp;
        tile[c][tp] = isb ? bf2f(((const bf16*)xin)[idx]) : ((const float*)xin)[idx];
    }
    __syncthreads();
    const int wc = threadIdx.x & 31, wp = threadIdx.x >> 5;
    bf16* dst = X + (size_t)b * HW_ * C_;
    #pragma unroll
    for (int i = 0; i < 4; ++i) {
        const int p = wp + i * 8;
        dst[(size_t)(p0 + p) * C_ + c0 + wc] = __float2bfloat16(tile[wc][p]);
    }
}

// ---------- LayerNorm: wave-per-token, no LDS, no barriers (r16-verified) ----
typedef __attribute__((ext_vector_type(8))) unsigned short u16x8;
__global__ __launch_bounds__(512) void k_layernorm(const bf16* __restrict__ X,
                                                   const bf16* __restrict__ g,
                                                   const bf16* __restrict__ bta,
                                                   bf16* __restrict__ XN) {
    const int wid  = threadIdx.x >> 6;
    const int lane = threadIdx.x & 63;
    const size_t tok = (size_t)blockIdx.x * 8 + wid;
    const size_t base = tok * C_ + lane * 8;

    const u16x8 u = *reinterpret_cast<const u16x8*>(X + base);
    float v[8];
    float s = 0.f, s2 = 0.f;
    #pragma unroll
    for (int e = 0; e < 8; ++e) {
        v[e] = __uint_as_float((unsigned)u[e] << 16);
        s += v[e]; s2 += v[e] * v[e];
    }
    #pragma unroll
    for (int d = 1; d <= 32; d <<= 1) { s += __shfl_xor(s, d); s2 += __shfl_xor(s2, d); }
    const float m  = s * (1.0f / C_);
    const float va = s2 * (1.0f / C_) - m * m;
    const float r  = rsqrtf(va + 1e-5f);

    const u16x8 ug = *reinterpret_cast<const u16x8*>(g   + lane * 8);
    const u16x8 ub = *reinterpret_cast<const u16x8*>(bta + lane * 8);
    u16x8 o;
    #pragma unroll
    for (int e = 0; e < 8; ++e) {
        const float gf = __uint_as_float((unsigned)ug[e] << 16);
        const float bf = __uint_as_float((unsigned)ub[e] << 16);
        o[e] = f2bfu((v[e] - m) * r * gf + bf);
    }
    *reinterpret_cast<u16x8*>(XN + base) = o;
}

// ===================== 8-phase 256x256 GEMM (r12-verified) ===================
template <typename TADD, typename TO, bool GELU, bool ADD, bool FINAL>
__global__ __launch_bounds__(512, 2) void k_gemm8(const bf16* __restrict__ A,
                                                  const bf16* __restrict__ Wt,
                                                  const bf16* __restrict__ bias,
                                                  const TADD* __restrict__ addp,
                                                  TO* __restrict__ out,
                                                  const int* flag,
                                                  int N, int K) {
    __shared__ bf16 sA[2][2][128 * 64];
    __shared__ bf16 sB[2][2][128 * 64];
    const int tid  = threadIdx.x;
    const int lane = tid & 63;
    const int wid  = tid >> 6;
    const int wr   = wid >> 2;
    const int wc2  = wid & 3;
    const int bh   = wc2 >> 1;
    const int brl  = (wc2 & 1) * 64;

    const int nwg  = gridDim.x;
    const int orig = blockIdx.x;
    const int nx = nwg >> 3, rr_ = nwg & 7;
    const int xcd = orig & 7, offw = orig >> 3;
    const int wg = (xcd < rr_ ? xcd * (nx + 1) : rr_ * (nx + 1) + (xcd - rr_) * nx) + offw;
    const int gx = N >> 8;
    const int m0 = (wg / gx) * 256, n0 = (wg % gx) * 256;

    const f32x4 vz = {0.f, 0.f, 0.f, 0.f};
    f32x4 acc[8][4];
    #pragma unroll
    for (int i = 0; i < 8; ++i)
        #pragma unroll
        for (int j = 0; j < 4; ++j) acc[i][j] = vz;

    const int sr8  = lane >> 3;
    const int schk = (lane & 7) ^ sr8;
    const bf16* gA0 = A  + (size_t)(m0 + sr8) * K + schk * 8;
    const bf16* gB0 = Wt + (size_t)(n0 + sr8) * K + schk * 8;

    const int l15 = lane & 15, g4 = lane >> 4;
    const int NTL = K >> 6;
    const int NITER = NTL >> 1;

    auto stageA = [&](int d, int h, int T) {
        const int kt = T << 6;
        #pragma unroll
        for (int p = 0; p < 2; ++p) {
            const int q = wid * 2 + p;
            __builtin_amdgcn_global_load_lds(
                AS1(gA0 + (size_t)(h * 128 + q * 8) * K + kt),
                AS3(&sA[d][h][q * 512]), 16, 0, 0);
        }
    };
    auto stageB = [&](int d, int h, int T) {
        const int kt = T << 6;
        #pragma unroll
        for (int p = 0; p < 2; ++p) {
            const int q = wid * 2 + p;
            __builtin_amdgcn_global_load_lds(
                AS1(gB0 + (size_t)(h * 128 + q * 8) * K + kt),
                AS3(&sB[d][h][q * 512]), 16, 0, 0);
        }
    };

    stageA(0, 0, 0); stageA(0, 1, 0);
    stageB(0, 0, 0); stageB(0, 1, 0);
    stageB(1, 0, 1); stageB(1, 1, 1);
    asm volatile("s_waitcnt vmcnt(4)" ::: "memory");
    __builtin_amdgcn_s_barrier();

    #pragma unroll 1
    for (int it = 0; it < NITER; ++it) {
        const bool nl = (it < NITER - 1);
        #pragma unroll
        for (int half = 0; half < 2; ++half) {
            bf16x8 bfr[4][2];
            #pragma unroll
            for (int q = 0; q < 4; ++q) {
                if (q == 0) {
                    #pragma unroll
                    for (int ks = 0; ks < 2; ++ks) {
                        const int ch = ((ks << 2) | g4) ^ (l15 & 7);
                        #pragma unroll
                        for (int j = 0; j < 4; ++j) {
                            const int r = brl + j * 16 + l15;
                            bfr[j][ks] = *reinterpret_cast<const bf16x8*>(&sB[half][bh][r * 64 + ch * 8]);
                        }
                    }
                }
                bf16x8 af[2][2];
                #pragma unroll
                for (int ks = 0; ks < 2; ++ks) {
                    const int ch = ((ks << 2) | g4) ^ (l15 & 7);
                    #pragma unroll
                    for (int ii = 0; ii < 2; ++ii) {
                        const int r = (q * 2 + ii) * 16 + l15;
                        af[ii][ks] = *reinterpret_cast<const bf16x8*>(&sA[half][wr][r * 64 + ch * 8]);
                    }
                }
                if (half == 0) {
                    if (q == 0)            { stageA(1, 0, 2 * it + 1); stageA(1, 1, 2 * it + 1); }
                    else if (q == 1 && nl) { stageB(0, 0, 2 * it + 2); }
                    else if (q == 2 && nl) { stageB(0, 1, 2 * it + 2); }
                } else {
                    if (q == 0 && nl)      { stageA(0, 0, 2 * it + 2); }
                    else if (q == 1 && nl) { stageA(0, 1, 2 * it + 2); }
                    else if (q == 2 && nl) { stageB(1, 0, 2 * it + 3); }
                    else if (q == 3 && nl) { stageB(1, 1, 2 * it + 3); }
                }
                __builtin_amdgcn_s_barrier();
                asm volatile("s_waitcnt lgkmcnt(0)" ::: "memory");
                __builtin_amdgcn_s_setprio(1);
                #pragma unroll
                for (int ks = 0; ks < 2; ++ks)
                    #pragma unroll
                    for (int ii = 0; ii < 2; ++ii)
                        #pragma unroll
                        for (int j = 0; j < 4; ++j)
                            acc[q * 2 + ii][j] = __builtin_amdgcn_mfma_f32_16x16x32_bf16(
                                af[ii][ks], bfr[j][ks], acc[q * 2 + ii][j], 0, 0, 0);
                __builtin_amdgcn_s_setprio(0);
                if (q == 3) {
                    if (half == 0) {
                        if (nl) asm volatile("s_waitcnt vmcnt(4)" ::: "memory");
                        else    asm volatile("s_waitcnt vmcnt(0)" ::: "memory");
                    } else if (nl) {
                        asm volatile("s_waitcnt vmcnt(4)" ::: "memory");
                    }
                }
                __builtin_amdgcn_s_barrier();
            }
        }
    }

    int obf = 0;
    if constexpr (FINAL) obf = *flag;
    const int colBase = n0 + wc2 * 64 + l15;
    const int rowTop  = m0 + wr * 128 + g4 * 4;
    float bc[4];
    #pragma unroll
    for (int j = 0; j < 4; ++j) bc[j] = bf2f(bias[colBase + j * 16]);
    #pragma unroll
    for (int i = 0; i < 8; ++i) {
        #pragma unroll
        for (int r = 0; r < 4; ++r) {
            const int row = rowTop + i * 16 + r;
            #pragma unroll
            for (int j = 0; j < 4; ++j) {
                const int col = colBase + j * 16;
                float v = acc[i][j][r] + bc[j];
                if constexpr (GELU) v = gelu_t(v);
                if constexpr (ADD)  v += rdv(&addp[(size_t)row * N + col]);
                if constexpr (FINAL) {
                    if (obf) ((bf16*)(void*)out)[(size_t)row * N + col] = __float2bfloat16(v);
                    else     ((float*)(void*)out)[(size_t)row * N + col] = v;
                } else {
                    stv(&out[(size_t)row * N + col], v);
                }
            }
        }
    }
}

// ========== direct streaming GEMM (no LDS, no barriers) for N=512 ============
// B (N*K*2 bytes) is L2-resident; each wave independently computes a 64x64
// tile reading A/B fragments straight from global in MFMA register layout.
// Block = 4 waves sharing the same 64 A-rows (L1/L2 reuse); grid = (M/64)*2.
template <typename TADD, bool ADD>
__global__ __launch_bounds__(256) void k_gemm_dir(const bf16* __restrict__ A,
                                                  const bf16* __restrict__ Wt,
                                                  const bf16* __restrict__ bias,
                                                  const TADD* __restrict__ addp,
                                                  bf16* __restrict__ out,
                                                  int N, int K) {
    const int lane = threadIdx.x & 63;
    const int w    = threadIdx.x >> 6;              // 0..3
    const int l15  = lane & 15, g4 = lane >> 4;
    const int m0   = (blockIdx.x >> 1) * 64;
    const int n0   = (blockIdx.x & 1) * 256 + w * 64;

    const f32x4 vz = {0.f, 0.f, 0.f, 0.f};
    f32x4 acc[4][4];
    #pragma unroll
    for (int i = 0; i < 4; ++i)
        #pragma unroll
        for (int j = 0; j < 4; ++j) acc[i][j] = vz;

    const bf16* Ar[4];
    const bf16* Br[4];
    #pragma unroll
    for (int f = 0; f < 4; ++f) {
        Ar[f] = A  + (size_t)(m0 + f * 16 + l15) * K + g4 * 8;
        Br[f] = Wt + (size_t)(n0 + f * 16 + l15) * K + g4 * 8;
    }

    #pragma unroll 4
    for (int kt = 0; kt < K; kt += 32) {
        bf16x8 af[4], bf_[4];
        #pragma unroll
        for (int f = 0; f < 4; ++f) {
            af[f]  = *reinterpret_cast<const bf16x8*>(Ar[f] + kt);
            bf_[f] = *reinterpret_cast<const bf16x8*>(Br[f] + kt);
        }
        #pragma unroll
        for (int i = 0; i < 4; ++i)
            #pragma unroll
            for (int j = 0; j < 4; ++j)
                acc[i][j] = __builtin_amdgcn_mfma_f32_16x16x32_bf16(af[i], bf_[j], acc[i][j], 0, 0, 0);
    }

    // C/D layout (m89): col = lane&15, row = (lane>>4)*4 + reg; j innermost.
    const int colBase = n0 + l15;
    const int rowTop  = m0 + g4 * 4;
    float bc[4];
    #pragma unroll
    for (int j = 0; j < 4; ++j) bc[j] = bf2f(bias[colBase + j * 16]);
    #pragma unroll
    for (int i = 0; i < 4; ++i) {
        #pragma unroll
        for (int r = 0; r < 4; ++r) {
            const int row = rowTop + i * 16 + r;
            #pragma unroll
            for (int j = 0; j < 4; ++j) {
                const int col = colBase + j * 16;
                float v = acc[i][j][r] + bc[j];
                if constexpr (ADD) v += rdv(&addp[(size_t)row * N + col]);
                out[(size_t)row * N + col] = __float2bfloat16(v);
            }
        }
    }
}

// ---------- combined bias(+mask) tables ----------
__global__ __launch_bounds__(256) void k_mktbl(const bf16* __restrict__ table,
                                               bf16* __restrict__ out, int shifted) {
    const int bh = blockIdx.x;
    const int cls = bh >> 4, h = bh & 15;
    const int rowE = shifted ? (cls >> 1) : 0;
    const int colE = shifted ? (cls & 1) : 0;
    for (int e = threadIdx.x; e < 64 * 64; e += 256) {
        const int i = e >> 6, j = e & 63;
        float v;
        if (i < NT_ && j < NT_) {
            const int yi = i / WS_, xi = i % WS_, yj = j / WS_, xj = j % WS_;
            const int ridx = (yi - yj + 6) * 13 + (xi - xj + 6);
            v = bf2f(table[ridx * NH_ + h]);
            const int ri = (rowE ? (yi < 4 ? 1 : 2) : 0) * 3 + (colE ? (xi < 4 ? 1 : 2) : 0);
            const int rj = (rowE ? (yj < 4 ? 1 : 2) : 0) * 3 + (colE ? (xj < 4 ? 1 : 2) : 0);
            if (ri != rj) v -= 100.f;
        } else if (j >= NT_) {
            v = -3e30f;
        } else {
            v = 0.f;
        }
        out[((size_t)bh << 12) + e] = __float2bfloat16(v);
    }
}

// ---------- MFMA window attention ----------
template <int SS, bool SHIFTED>
__global__ __launch_bounds__(64) void k_attn_mfma(const bf16* __restrict__ QKV,
                                                  const bf16* __restrict__ tbl,
                                                  bf16* __restrict__ O) {
    __shared__ __align__(16) short uQK[5120];
    __shared__ __align__(16) short uVt[2304];
    __shared__ int toks[NT_];
    short* Qs = uQK;
    short* Ks = uQK + 2560;
    short* Ps = uQK;

    const int lane = threadIdx.x;
    const int head = blockIdx.x & 15;
    const int win  = blockIdx.x >> 4;
    const int bl = win >> 6, w64 = win & 63;
    const int wy = w64 >> 3, wx = w64 & 7;

    if (lane < NT_) {
        const int dy = lane / WS_, dx = lane % WS_;
        const int sr = wy * WS_ + dy, scn = wx * WS_ + dx;
        const int r = (sr + SS) % H_, c = (scn + SS) % W_;
        toks[lane] = bl * HW_ + r * W_ + c;
    }
    __syncthreads();

    const int g4 = lane >> 4, l15 = lane & 15;
    const int tsg = lane >> 2, csg = (lane & 3) * 8;

    #pragma unroll
    for (int rr = 0; rr < 4; ++rr) {
        const int t = rr * 16 + tsg;
        bf16x8 qv = {0,0,0,0,0,0,0,0}, kv = {0,0,0,0,0,0,0,0}, vv = {0,0,0,0,0,0,0,0};
        if (t < NT_) {
            const bf16* base = QKV + (size_t)toks[t] * 1536 + head * HD_ + csg;
            qv = *reinterpret_cast<const bf16x8*>(base);
            kv = *reinterpret_cast<const bf16x8*>(base + 512);
            vv = *reinterpret_cast<const bf16x8*>(base + 1024);
        }
        *reinterpret_cast<bf16x8*>(&Qs[t * 40 + csg]) = qv;
        *reinterpret_cast<bf16x8*>(&Ks[t * 40 + csg]) = kv;
        #pragma unroll
        for (int e = 0; e < 8; ++e) uVt[(csg + e) * 72 + t] = ((const short*)&vv)[e];
    }
    __syncthreads();

    bf16x8 aq[4], bk[4];
    #pragma unroll
    for (int f = 0; f < 4; ++f) {
        aq[f] = *reinterpret_cast<const bf16x8*>(&Qs[(f * 16 + l15) * 40 + g4 * 8]);
        bk[f] = *reinterpret_cast<const bf16x8*>(&Ks[(f * 16 + l15) * 40 + g4 * 8]);
    }
    const f32x4 vz = {0.f, 0.f, 0.f, 0.f};
    f32x4 sacc[4][4];
    #pragma unroll
    for (int qi = 0; qi < 4; ++qi)
        #pragma unroll
        for (int kj = 0; kj < 4; ++kj)
            sacc[qi][kj] = __builtin_amdgcn_mfma_f32_16x16x32_bf16(aq[qi], bk[kj], vz, 0, 0, 0);
    __syncthreads();

    const int cls = SHIFTED ? (((wy == 7) ? 2 : 0) + ((wx == 7) ? 1 : 0)) : 0;
    const bf16* tb = tbl + (((size_t)(cls * NH_ + head)) << 12);
    const float scale = 0.17677669529663687f;
    #pragma unroll
    for (int qi = 0; qi < 4; ++qi) {
        #pragma unroll
        for (int r = 0; r < 4; ++r) {
            const int i = qi * 16 + g4 * 4 + r;
            const bf16* trow = tb + (i << 6);
            float sv[4];
            #pragma unroll
            for (int kj = 0; kj < 4; ++kj)
                sv[kj] = sacc[qi][kj][r] * scale + bf2f(trow[kj * 16 + l15]);
            float mx = fmaxf(fmaxf(sv[0], sv[1]), fmaxf(sv[2], sv[3]));
            #pragma unroll
            for (int d = 1; d <= 8; d <<= 1) mx = fmaxf(mx, __shfl_xor(mx, d));
            float p[4], sum = 0.f;
            #pragma unroll
            for (int kj = 0; kj < 4; ++kj) { p[kj] = __expf(sv[kj] - mx); sum += p[kj]; }
            #pragma unroll
            for (int d = 1; d <= 8; d <<= 1) sum += __shfl_xor(sum, d);
            const float inv = 1.0f / sum;
            #pragma unroll
            for (int kj = 0; kj < 4; ++kj)
                Ps[i * 72 + kj * 16 + l15] = (short)f2bfu(p[kj] * inv);
        }
    }
    __syncthreads();

    f32x4 oacc[4][2];
    #pragma unroll
    for (int qi = 0; qi < 4; ++qi) { oacc[qi][0] = vz; oacc[qi][1] = vz; }
    #pragma unroll
    for (int ks = 0; ks < 2; ++ks) {
        bf16x8 bv[2];
        #pragma unroll
        for (int dj = 0; dj < 2; ++dj)
            bv[dj] = *reinterpret_cast<const bf16x8*>(&uVt[(dj * 16 + l15) * 72 + ks * 32 + g4 * 8]);
        #pragma unroll
        for (int qi = 0; qi < 4; ++qi) {
            const bf16x8 ap = *reinterpret_cast<const bf16x8*>(&Ps[(qi * 16 + l15) * 72 + ks * 32 + g4 * 8]);
            #pragma unroll
            for (int dj = 0; dj < 2; ++dj)
                oacc[qi][dj] = __builtin_amdgcn_mfma_f32_16x16x32_bf16(ap, bv[dj], oacc[qi][dj], 0, 0, 0);
        }
    }
    #pragma unroll
    for (int qi = 0; qi < 4; ++qi) {
        #pragma unroll
        for (int r = 0; r < 4; ++r) {
            const int i = qi * 16 + g4 * 4 + r;
            if (i < NT_) {
                const size_t ob = (size_t)toks[i] * C_ + head * HD_ + l15;
                O[ob]      = __float2bfloat16(oacc[qi][0][r]);
                O[ob + 16] = __float2bfloat16(oacc[qi][1][r]);
            }
        }
    }
}

// ---------- launch ----------
extern "C" void kernel_launch(void* const* d_in, const int* in_sizes, int n_in,
                              void* d_out, int out_size, void* d_ws, size_t ws_size,
                              hipStream_t stream) {
    (void)out_size; (void)ws_size;
    char* ws = (char*)d_ws;
    const size_t WEIGHT_RESERVE = 12651520;
    bf16*  WC   = (bf16*)ws;
    int*   FLG  = (int*)(ws + WEIGHT_RESERVE);
    bf16*  TBL1 = (bf16*)(ws + WEIGHT_RESERVE + 1024);
    bf16*  TBL2 = (bf16*)(ws + WEIGHT_RESERVE + 1024 + 131072);
    bf16*  X    = (bf16*)(ws + WEIGHT_RESERVE + 656384);
    bf16*  XN   = X + (size_t)M_ * C_;
    char*  BIG  = (char*)(XN + (size_t)M_ * C_);

    size_t offs[27];
    size_t off = 0;
    for (int i = 1; i < n_in && i < 27; ++i) { offs[i] = off; off += (size_t)((in_sizes[i] + 7) & ~7); }
    auto wc = [&](int i) { return (const bf16*)(WC + offs[i]); };

    k_detect<<<1, 1, 0, stream>>>(d_in[1], FLG);
    {
        WArgs a;
        for (int i = 1; i < 27; ++i) {
            a.src[i - 1] = d_in[i];
            a.dst[i - 1] = WC + offs[i];
            a.n[i - 1]   = in_sizes[i];
        }
        k_convert_all<<<512, 256, 0, stream>>>(a, FLG);
    }
    k_mktbl<<<16, 256, 0, stream>>>(wc(7),  TBL1, 0);
    k_mktbl<<<64, 256, 0, stream>>>(wc(20), TBL2, 1);

    const dim3 gT(HW_ / 32, C_ / 32, B_);
    k_transpose_in<<<gT, 256, 0, stream>>>(d_in[0], X, FLG);

    bf16* QKV = (bf16*)BIG;
    bf16* ATT = (bf16*)(BIG + (size_t)M_ * 1536 * 2);
    bf16* HID = (bf16*)BIG;

    const int gQ = (1536 / 256) * (M_ / 256);   // 588  (qkv, 8-phase 256^2)
    const int gF = (2048 / 256) * (M_ / 256);   // 784  (fc1, 8-phase 256^2)
    const int gD = (M_ / 64) * 2;               // 784  (proj, direct streaming)
    const int gO = (512 / 256)  * (M_ / 256);   // 196  (fc2, 8-phase 256^2)
    const int gL = M_ / 8;                      // 3136 (LN)
    const dim3 gA(B_ * 64 * NH_);

    // ================= branch 1: window attention =================
    k_layernorm<<<gL, 512, 0, stream>>>(X, wc(1), wc(2), XN);
    k_gemm8<bf16, bf16, false, false, false><<<gQ, 512, 0, stream>>>(
        XN, wc(3), wc(4), (const bf16*)nullptr, QKV, nullptr, 1536, C_);
    k_attn_mfma<0, false><<<gA, 64, 0, stream>>>(QKV, TBL1, ATT);
    k_gemm_dir<bf16, true><<<gD, 256, 0, stream>>>(
        ATT, wc(5), wc(6), X, X, C_, C_);
    // ================= MLP 1 =================
    k_layernorm<<<gL, 512, 0, stream>>>(X, wc(8), wc(9), XN);
    k_gemm8<bf16, bf16, true, false, false><<<gF, 512, 0, stream>>>(
        XN, wc(10), wc(11), (const bf16*)nullptr, HID, nullptr, 2048, C_);
    k_gemm8<bf16, bf16, false, true, false><<<gO, 512, 0, stream>>>(
        HID, wc(12), wc(13), X, X, nullptr, C_, 2048);
    // ============ branch 2: shifted window attention (residual = XN) ============
    k_layernorm<<<gL, 512, 0, stream>>>(X, wc(14), wc(15), XN);
    k_gemm8<bf16, bf16, false, false, false><<<gQ, 512, 0, stream>>>(
        XN, wc(16), wc(17), (const bf16*)nullptr, QKV, nullptr, 1536, C_);
    k_attn_mfma<3, true><<<gA, 64, 0, stream>>>(QKV, TBL2, ATT);
    k_gemm_dir<bf16, true><<<gD, 256, 0, stream>>>(
        ATT, wc(18), wc(19), XN, X, C_, C_);
    // ================= MLP 2 (final -> d_out, dtype per flag) =================
    k_layernorm<<<gL, 512, 0, stream>>>(X, wc(21), wc(22), XN);
    k_gemm8<bf16, bf16, true, false, false><<<gF, 512, 0, stream>>>(
        XN, wc(23), wc(24), (const bf16*)nullptr, HID, nullptr, 2048, C_);
    k_gemm8<bf16, float, false, true, true><<<gO, 512, 0, stream>>>(
        HID, wc(25), wc(26), X, (float*)d_out, FLG, C_, 2048);
}

// Round 18
// 781.325 us; speedup vs baseline: 1.0856x; 1.0856x over previous
//
#include <hip/hip_runtime.h>
#include <hip/hip_bf16.h>

using bf16 = __hip_bfloat16;

#define B_      8
#define C_      512
#define H_      56
#define W_      56
#define HW_     3136
#define M_      25088   // B_*HW_
#define NH_     16
#define HD_     32
#define WS_     7
#define NT_     49

typedef __attribute__((ext_vector_type(8))) short bf16x8;
typedef __attribute__((ext_vector_type(4))) float f32x4;

#define AS1(p) ((const __attribute__((address_space(1))) void*)(p))
#define AS3(p) ((__attribute__((address_space(3))) void*)(p))

// ---------- helpers ----------
__device__ inline float bf2f(const bf16 v) {
    unsigned short u = *reinterpret_cast<const unsigned short*>(&v);
    return __uint_as_float((unsigned)u << 16);
}
__device__ inline unsigned short f2bfu(float f) {
    bf16 h = __float2bfloat16(f);
    return *reinterpret_cast<unsigned short*>(&h);
}
__device__ inline float rdv(const float* p) { return *p; }
__device__ inline float rdv(const bf16* p)  { return bf2f(*p); }
__device__ inline void stv(float* p, float v) { *p = v; }
__device__ inline void stv(bf16* p, float v)  { *p = __float2bfloat16(v); }

__device__ inline float gelu_t(float v) {
    const float u = v * (0.79788456080286536f + 0.035677408136300125f * v * v);
    const float e = __expf(2.0f * u);
    return 0.5f * v * (2.0f - 2.0f / (e + 1.0f));
}

// ---------- dtype detector ----------
__global__ void k_detect(const void* g1, int* flag) {
    const unsigned short* u = (const unsigned short*)g1;
    *flag = (u[0] == 0x3F80u) ? 1 : 0;
}

// ---------- fused weight conversion ----------
struct WArgs {
    const void* src[26];
    bf16*       dst[26];
    int         n[26];
};
__global__ __launch_bounds__(256) void k_convert_all(WArgs a, const int* flag) {
    const int isb = *flag;
    const int gid = blockIdx.x * 256 + threadIdx.x;
    const int stride = gridDim.x * 256;
    #pragma unroll 1
    for (int w = 0; w < 26; ++w) {
        const int n = a.n[w];
        bf16* d = a.dst[w];
        if (isb) {
            const unsigned short* s = (const unsigned short*)a.src[w];
            for (int i = gid; i < n; i += stride) ((unsigned short*)d)[i] = s[i];
        } else {
            const float* s = (const float*)a.src[w];
            for (int i = gid; i < n; i += stride) d[i] = __float2bfloat16(s[i]);
        }
    }
}

// ---------- input transpose ----------
__global__ __launch_bounds__(256) void k_transpose_in(const void* xin, bf16* X,
                                                      const int* flag) {
    __shared__ float tile[32][33];
    const int isb = *flag;
    const int p0 = blockIdx.x * 32, c0 = blockIdx.y * 32, b = blockIdx.z;
    const int tp = threadIdx.x & 31, tc = threadIdx.x >> 5;
    const size_t ibase = (size_t)b * C_ * HW_;
    #pragma unroll
    for (int i = 0; i < 4; ++i) {
        const int c = tc + i * 8;
        const size_t idx = ibase + (size_t)(c0 + c) * HW_ + p0 + tp;
        tile[c][tp] = isb ? bf2f(((const bf16*)xin)[idx]) : ((const float*)xin)[idx];
    }
    __syncthreads();
    const int wc = threadIdx.x & 31, wp = threadIdx.x >> 5;
    bf16* dst = X + (size_t)b * HW_ * C_;
    #pragma unroll
    for (int i = 0; i < 4; ++i) {
        const int p = wp + i * 8;
        dst[(size_t)(p0 + p) * C_ + c0 + wc] = __float2bfloat16(tile[wc][p]);
    }
}

// ---------- LayerNorm: wave-per-token, no LDS, no barriers (r16-verified) ----
typedef __attribute__((ext_vector_type(8))) unsigned short u16x8;
__global__ __launch_bounds__(512) void k_layernorm(const bf16* __restrict__ X,
                                                   const bf16* __restrict__ g,
                                                   const bf16* __restrict__ bta,
                                                   bf16* __restrict__ XN) {
    const int wid  = threadIdx.x >> 6;
    const int lane = threadIdx.x & 63;
    const size_t tok = (size_t)blockIdx.x * 8 + wid;
    const size_t base = tok * C_ + lane * 8;

    const u16x8 u = *reinterpret_cast<const u16x8*>(X + base);
    float v[8];
    float s = 0.f, s2 = 0.f;
    #pragma unroll
    for (int e = 0; e < 8; ++e) {
        v[e] = __uint_as_float((unsigned)u[e] << 16);
        s += v[e]; s2 += v[e] * v[e];
    }
    #pragma unroll
    for (int d = 1; d <= 32; d <<= 1) { s += __shfl_xor(s, d); s2 += __shfl_xor(s2, d); }
    const float m  = s * (1.0f / C_);
    const float va = s2 * (1.0f / C_) - m * m;
    const float r  = rsqrtf(va + 1e-5f);

    const u16x8 ug = *reinterpret_cast<const u16x8*>(g   + lane * 8);
    const u16x8 ub = *reinterpret_cast<const u16x8*>(bta + lane * 8);
    u16x8 o;
    #pragma unroll
    for (int e = 0; e < 8; ++e) {
        const float gf = __uint_as_float((unsigned)ug[e] << 16);
        const float bf = __uint_as_float((unsigned)ub[e] << 16);
        o[e] = f2bfu((v[e] - m) * r * gf + bf);
    }
    *reinterpret_cast<u16x8*>(XN + base) = o;
}

// ===================== 8-phase 256x256 GEMM (r12-verified) ===================
template <typename TADD, typename TO, bool GELU, bool ADD, bool FINAL>
__global__ __launch_bounds__(512, 2) void k_gemm8(const bf16* __restrict__ A,
                                                  const bf16* __restrict__ Wt,
                                                  const bf16* __restrict__ bias,
                                                  const TADD* __restrict__ addp,
                                                  TO* __restrict__ out,
                                                  const int* flag,
                                                  int N, int K) {
    __shared__ bf16 sA[2][2][128 * 64];
    __shared__ bf16 sB[2][2][128 * 64];
    const int tid  = threadIdx.x;
    const int lane = tid & 63;
    const int wid  = tid >> 6;
    const int wr   = wid >> 2;
    const int wc2  = wid & 3;
    const int bh   = wc2 >> 1;
    const int brl  = (wc2 & 1) * 64;

    const int nwg  = gridDim.x;
    const int orig = blockIdx.x;
    const int nx = nwg >> 3, rr_ = nwg & 7;
    const int xcd = orig & 7, offw = orig >> 3;
    const int wg = (xcd < rr_ ? xcd * (nx + 1) : rr_ * (nx + 1) + (xcd - rr_) * nx) + offw;
    const int gx = N >> 8;
    const int m0 = (wg / gx) * 256, n0 = (wg % gx) * 256;

    const f32x4 vz = {0.f, 0.f, 0.f, 0.f};
    f32x4 acc[8][4];
    #pragma unroll
    for (int i = 0; i < 8; ++i)
        #pragma unroll
        for (int j = 0; j < 4; ++j) acc[i][j] = vz;

    const int sr8  = lane >> 3;
    const int schk = (lane & 7) ^ sr8;
    const bf16* gA0 = A  + (size_t)(m0 + sr8) * K + schk * 8;
    const bf16* gB0 = Wt + (size_t)(n0 + sr8) * K + schk * 8;

    const int l15 = lane & 15, g4 = lane >> 4;
    const int NTL = K >> 6;
    const int NITER = NTL >> 1;

    auto stageA = [&](int d, int h, int T) {
        const int kt = T << 6;
        #pragma unroll
        for (int p = 0; p < 2; ++p) {
            const int q = wid * 2 + p;
            __builtin_amdgcn_global_load_lds(
                AS1(gA0 + (size_t)(h * 128 + q * 8) * K + kt),
                AS3(&sA[d][h][q * 512]), 16, 0, 0);
        }
    };
    auto stageB = [&](int d, int h, int T) {
        const int kt = T << 6;
        #pragma unroll
        for (int p = 0; p < 2; ++p) {
            const int q = wid * 2 + p;
            __builtin_amdgcn_global_load_lds(
                AS1(gB0 + (size_t)(h * 128 + q * 8) * K + kt),
                AS3(&sB[d][h][q * 512]), 16, 0, 0);
        }
    };

    stageA(0, 0, 0); stageA(0, 1, 0);
    stageB(0, 0, 0); stageB(0, 1, 0);
    stageB(1, 0, 1); stageB(1, 1, 1);
    asm volatile("s_waitcnt vmcnt(4)" ::: "memory");
    __builtin_amdgcn_s_barrier();

    #pragma unroll 1
    for (int it = 0; it < NITER; ++it) {
        const bool nl = (it < NITER - 1);
        #pragma unroll
        for (int half = 0; half < 2; ++half) {
            bf16x8 bfr[4][2];
            #pragma unroll
            for (int q = 0; q < 4; ++q) {
                if (q == 0) {
                    #pragma unroll
                    for (int ks = 0; ks < 2; ++ks) {
                        const int ch = ((ks << 2) | g4) ^ (l15 & 7);
                        #pragma unroll
                        for (int j = 0; j < 4; ++j) {
                            const int r = brl + j * 16 + l15;
                            bfr[j][ks] = *reinterpret_cast<const bf16x8*>(&sB[half][bh][r * 64 + ch * 8]);
                        }
                    }
                }
                bf16x8 af[2][2];
                #pragma unroll
                for (int ks = 0; ks < 2; ++ks) {
                    const int ch = ((ks << 2) | g4) ^ (l15 & 7);
                    #pragma unroll
                    for (int ii = 0; ii < 2; ++ii) {
                        const int r = (q * 2 + ii) * 16 + l15;
                        af[ii][ks] = *reinterpret_cast<const bf16x8*>(&sA[half][wr][r * 64 + ch * 8]);
                    }
                }
                if (half == 0) {
                    if (q == 0)            { stageA(1, 0, 2 * it + 1); stageA(1, 1, 2 * it + 1); }
                    else if (q == 1 && nl) { stageB(0, 0, 2 * it + 2); }
                    else if (q == 2 && nl) { stageB(0, 1, 2 * it + 2); }
                } else {
                    if (q == 0 && nl)      { stageA(0, 0, 2 * it + 2); }
                    else if (q == 1 && nl) { stageA(0, 1, 2 * it + 2); }
                    else if (q == 2 && nl) { stageB(1, 0, 2 * it + 3); }
                    else if (q == 3 && nl) { stageB(1, 1, 2 * it + 3); }
                }
                __builtin_amdgcn_s_barrier();
                asm volatile("s_waitcnt lgkmcnt(0)" ::: "memory");
                __builtin_amdgcn_s_setprio(1);
                #pragma unroll
                for (int ks = 0; ks < 2; ++ks)
                    #pragma unroll
                    for (int ii = 0; ii < 2; ++ii)
                        #pragma unroll
                        for (int j = 0; j < 4; ++j)
                            acc[q * 2 + ii][j] = __builtin_amdgcn_mfma_f32_16x16x32_bf16(
                                af[ii][ks], bfr[j][ks], acc[q * 2 + ii][j], 0, 0, 0);
                __builtin_amdgcn_s_setprio(0);
                if (q == 3) {
                    if (half == 0) {
                        if (nl) asm volatile("s_waitcnt vmcnt(4)" ::: "memory");
                        else    asm volatile("s_waitcnt vmcnt(0)" ::: "memory");
                    } else if (nl) {
                        asm volatile("s_waitcnt vmcnt(4)" ::: "memory");
                    }
                }
                __builtin_amdgcn_s_barrier();
            }
        }
    }

    int obf = 0;
    if constexpr (FINAL) obf = *flag;
    const int colBase = n0 + wc2 * 64 + l15;
    const int rowTop  = m0 + wr * 128 + g4 * 4;
    float bc[4];
    #pragma unroll
    for (int j = 0; j < 4; ++j) bc[j] = bf2f(bias[colBase + j * 16]);
    #pragma unroll
    for (int i = 0; i < 8; ++i) {
        #pragma unroll
        for (int r = 0; r < 4; ++r) {
            const int row = rowTop + i * 16 + r;
            #pragma unroll
            for (int j = 0; j < 4; ++j) {
                const int col = colBase + j * 16;
                float v = acc[i][j][r] + bc[j];
                if constexpr (GELU) v = gelu_t(v);
                if constexpr (ADD)  v += rdv(&addp[(size_t)row * N + col]);
                if constexpr (FINAL) {
                    if (obf) ((bf16*)(void*)out)[(size_t)row * N + col] = __float2bfloat16(v);
                    else     ((float*)(void*)out)[(size_t)row * N + col] = v;
                } else {
                    stv(&out[(size_t)row * N + col], v);
                }
            }
        }
    }
}

// ===================== 256x128, BK=64, NBUF=3 (proj; r11/r12-verified) =======
template <typename TADD, typename TO, bool GELU, bool ADD, bool FINAL>
__global__ __launch_bounds__(512, 2) void k_gemm_mfma(const bf16* __restrict__ A,
                                                      const bf16* __restrict__ Wt,
                                                      const bf16* __restrict__ bias,
                                                      const TADD* __restrict__ addp,
                                                      TO* __restrict__ out,
                                                      const int* flag,
                                                      int N, int K) {
    __shared__ bf16 sA[3][256 * 64];
    __shared__ bf16 sB[3][128 * 64];
    const int tid  = threadIdx.x;
    const int lane = tid & 63;
    const int wid  = tid >> 6;
    const int wr   = wid >> 1;
    const int wc2  = wid & 1;

    const int nwg  = gridDim.x;
    const int orig = blockIdx.x;
    const int nx = nwg >> 3, rr_ = nwg & 7;
    const int xcd = orig & 7, offw = orig >> 3;
    const int wg = (xcd < rr_ ? xcd * (nx + 1) : rr_ * (nx + 1) + (xcd - rr_) * nx) + offw;
    const int gx = N >> 7;
    const int m0 = (wg / gx) * 256, n0 = (wg % gx) * 128;

    const f32x4 vz = {0.f, 0.f, 0.f, 0.f};
    f32x4 acc[4][4];
    #pragma unroll
    for (int i = 0; i < 4; ++i)
        #pragma unroll
        for (int j = 0; j < 4; ++j) acc[i][j] = vz;

    const int sr8  = lane >> 3;
    const int schk = (lane & 7) ^ sr8;
    const bf16* gA0 = A  + (size_t)(m0 + sr8) * K + schk * 8;
    const bf16* gB0 = Wt + (size_t)(n0 + sr8) * K + schk * 8;

    const int l15 = lane & 15, g4 = lane >> 4;
    const int NTLE = K >> 6;

    #pragma unroll
    for (int tt = 0; tt < 3; ++tt) {
        const int kt = tt << 6;
        #pragma unroll
        for (int p = 0; p < 4; ++p) {
            const int q = wid * 4 + p;
            __builtin_amdgcn_global_load_lds(AS1(gA0 + (size_t)(q * 8) * K + kt),
                                             AS3(&sA[tt][q * 512]), 16, 0, 0);
        }
        #pragma unroll
        for (int p = 0; p < 2; ++p) {
            const int q = wid * 2 + p;
            __builtin_amdgcn_global_load_lds(AS1(gB0 + (size_t)(q * 8) * K + kt),
                                             AS3(&sB[tt][q * 512]), 16, 0, 0);
        }
    }

    for (int t = 0; t < NTLE; ++t) {
        const int rem = NTLE - 1 - t;
        if (rem >= 2)      asm volatile("s_waitcnt vmcnt(12)" ::: "memory");
        else if (rem == 1) asm volatile("s_waitcnt vmcnt(6)"  ::: "memory");
        else               asm volatile("s_waitcnt vmcnt(0)"  ::: "memory");
        __builtin_amdgcn_s_barrier();

        const int buf = t % 3;
        bf16x8 bfr[4][2];
        #pragma unroll
        for (int ks = 0; ks < 2; ++ks) {
            const int ch = ((ks << 2) | g4) ^ (l15 & 7);
            #pragma unroll
            for (int j = 0; j < 4; ++j) {
                const int rowB = wc2 * 64 + j * 16 + l15;
                bfr[j][ks] = *reinterpret_cast<const bf16x8*>(&sB[buf][rowB * 64 + ch * 8]);
            }
        }
        const int ch0 = g4 ^ (l15 & 7);
        const int ch1 = (4 | g4) ^ (l15 & 7);
        __builtin_amdgcn_s_setprio(1);
        #pragma unroll
        for (int i = 0; i < 4; ++i) {
            const int rowA = wr * 64 + i * 16 + l15;
            const bf16x8 a0 = *reinterpret_cast<const bf16x8*>(&sA[buf][rowA * 64 + ch0 * 8]);
            const bf16x8 a1 = *reinterpret_cast<const bf16x8*>(&sA[buf][rowA * 64 + ch1 * 8]);
            #pragma unroll
            for (int j = 0; j < 4; ++j) {
                acc[i][j] = __builtin_amdgcn_mfma_f32_16x16x32_bf16(a0, bfr[j][0], acc[i][j], 0, 0, 0);
                acc[i][j] = __builtin_amdgcn_mfma_f32_16x16x32_bf16(a1, bfr[j][1], acc[i][j], 0, 0, 0);
            }
        }
        __builtin_amdgcn_s_setprio(0);

        asm volatile("s_waitcnt lgkmcnt(0)" ::: "memory");
        __builtin_amdgcn_s_barrier();

        const int tn = t + 3;
        if (tn < NTLE) {
            const int kt = tn << 6;
            #pragma unroll
            for (int p = 0; p < 4; ++p) {
                const int q = wid * 4 + p;
                __builtin_amdgcn_global_load_lds(AS1(gA0 + (size_t)(q * 8) * K + kt),
                                                 AS3(&sA[buf][q * 512]), 16, 0, 0);
            }
            #pragma unroll
            for (int p = 0; p < 2; ++p) {
                const int q = wid * 2 + p;
                __builtin_amdgcn_global_load_lds(AS1(gB0 + (size_t)(q * 8) * K + kt),
                                                 AS3(&sB[buf][q * 512]), 16, 0, 0);
            }
        }
    }

    int obf = 0;
    if constexpr (FINAL) obf = *flag;
    const int colBase = n0 + wc2 * 64 + l15;
    const int rowTop  = m0 + wr * 64 + g4 * 4;
    float bc[4];
    #pragma unroll
    for (int j = 0; j < 4; ++j) bc[j] = bf2f(bias[colBase + j * 16]);
    #pragma unroll
    for (int i = 0; i < 4; ++i) {
        #pragma unroll
        for (int r = 0; r < 4; ++r) {
            const int row = rowTop + i * 16 + r;
            #pragma unroll
            for (int j = 0; j < 4; ++j) {
                const int col = colBase + j * 16;
                float v = acc[i][j][r] + bc[j];
                if constexpr (GELU) v = gelu_t(v);
                if constexpr (ADD)  v += rdv(&addp[(size_t)row * N + col]);
                if constexpr (FINAL) {
                    if (obf) ((bf16*)(void*)out)[(size_t)row * N + col] = __float2bfloat16(v);
                    else     ((float*)(void*)out)[(size_t)row * N + col] = v;
                } else {
                    stv(&out[(size_t)row * N + col], v);
                }
            }
        }
    }
}

// ---------- combined bias(+mask) tables ----------
__global__ __launch_bounds__(256) void k_mktbl(const bf16* __restrict__ table,
                                               bf16* __restrict__ out, int shifted) {
    const int bh = blockIdx.x;
    const int cls = bh >> 4, h = bh & 15;
    const int rowE = shifted ? (cls >> 1) : 0;
    const int colE = shifted ? (cls & 1) : 0;
    for (int e = threadIdx.x; e < 64 * 64; e += 256) {
        const int i = e >> 6, j = e & 63;
        float v;
        if (i < NT_ && j < NT_) {
            const int yi = i / WS_, xi = i % WS_, yj = j / WS_, xj = j % WS_;
            const int ridx = (yi - yj + 6) * 13 + (xi - xj + 6);
            v = bf2f(table[ridx * NH_ + h]);
            const int ri = (rowE ? (yi < 4 ? 1 : 2) : 0) * 3 + (colE ? (xi < 4 ? 1 : 2) : 0);
            const int rj = (rowE ? (yj < 4 ? 1 : 2) : 0) * 3 + (colE ? (xj < 4 ? 1 : 2) : 0);
            if (ri != rj) v -= 100.f;
        } else if (j >= NT_) {
            v = -3e30f;
        } else {
            v = 0.f;
        }
        out[((size_t)bh << 12) + e] = __float2bfloat16(v);
    }
}

// ---------- MFMA window attention ----------
template <int SS, bool SHIFTED>
__global__ __launch_bounds__(64) void k_attn_mfma(const bf16* __restrict__ QKV,
                                                  const bf16* __restrict__ tbl,
                                                  bf16* __restrict__ O) {
    __shared__ __align__(16) short uQK[5120];
    __shared__ __align__(16) short uVt[2304];
    __shared__ int toks[NT_];
    short* Qs = uQK;
    short* Ks = uQK + 2560;
    short* Ps = uQK;

    const int lane = threadIdx.x;
    const int head = blockIdx.x & 15;
    const int win  = blockIdx.x >> 4;
    const int bl = win >> 6, w64 = win & 63;
    const int wy = w64 >> 3, wx = w64 & 7;

    if (lane < NT_) {
        const int dy = lane / WS_, dx = lane % WS_;
        const int sr = wy * WS_ + dy, scn = wx * WS_ + dx;
        const int r = (sr + SS) % H_, c = (scn + SS) % W_;
        toks[lane] = bl * HW_ + r * W_ + c;
    }
    __syncthreads();

    const int g4 = lane >> 4, l15 = lane & 15;
    const int tsg = lane >> 2, csg = (lane & 3) * 8;

    #pragma unroll
    for (int rr = 0; rr < 4; ++rr) {
        const int t = rr * 16 + tsg;
        bf16x8 qv = {0,0,0,0,0,0,0,0}, kv = {0,0,0,0,0,0,0,0}, vv = {0,0,0,0,0,0,0,0};
        if (t < NT_) {
            const bf16* base = QKV + (size_t)toks[t] * 1536 + head * HD_ + csg;
            qv = *reinterpret_cast<const bf16x8*>(base);
            kv = *reinterpret_cast<const bf16x8*>(base + 512);
            vv = *reinterpret_cast<const bf16x8*>(base + 1024);
        }
        *reinterpret_cast<bf16x8*>(&Qs[t * 40 + csg]) = qv;
        *reinterpret_cast<bf16x8*>(&Ks[t * 40 + csg]) = kv;
        #pragma unroll
        for (int e = 0; e < 8; ++e) uVt[(csg + e) * 72 + t] = ((const short*)&vv)[e];
    }
    __syncthreads();

    bf16x8 aq[4], bk[4];
    #pragma unroll
    for (int f = 0; f < 4; ++f) {
        aq[f] = *reinterpret_cast<const bf16x8*>(&Qs[(f * 16 + l15) * 40 + g4 * 8]);
        bk[f] = *reinterpret_cast<const bf16x8*>(&Ks[(f * 16 + l15) * 40 + g4 * 8]);
    }
    const f32x4 vz = {0.f, 0.f, 0.f, 0.f};
    f32x4 sacc[4][4];
    #pragma unroll
    for (int qi = 0; qi < 4; ++qi)
        #pragma unroll
        for (int kj = 0; kj < 4; ++kj)
            sacc[qi][kj] = __builtin_amdgcn_mfma_f32_16x16x32_bf16(aq[qi], bk[kj], vz, 0, 0, 0);
    __syncthreads();

    const int cls = SHIFTED ? (((wy == 7) ? 2 : 0) + ((wx == 7) ? 1 : 0)) : 0;
    const bf16* tb = tbl + (((size_t)(cls * NH_ + head)) << 12);
    const float scale = 0.17677669529663687f;
    #pragma unroll
    for (int qi = 0; qi < 4; ++qi) {
        #pragma unroll
        for (int r = 0; r < 4; ++r) {
            const int i = qi * 16 + g4 * 4 + r;
            const bf16* trow = tb + (i << 6);
            float sv[4];
            #pragma unroll
            for (int kj = 0; kj < 4; ++kj)
                sv[kj] = sacc[qi][kj][r] * scale + bf2f(trow[kj * 16 + l15]);
            float mx = fmaxf(fmaxf(sv[0], sv[1]), fmaxf(sv[2], sv[3]));
            #pragma unroll
            for (int d = 1; d <= 8; d <<= 1) mx = fmaxf(mx, __shfl_xor(mx, d));
            float p[4], sum = 0.f;
            #pragma unroll
            for (int kj = 0; kj < 4; ++kj) { p[kj] = __expf(sv[kj] - mx); sum += p[kj]; }
            #pragma unroll
            for (int d = 1; d <= 8; d <<= 1) sum += __shfl_xor(sum, d);
            const float inv = 1.0f / sum;
            #pragma unroll
            for (int kj = 0; kj < 4; ++kj)
                Ps[i * 72 + kj * 16 + l15] = (short)f2bfu(p[kj] * inv);
        }
    }
    __syncthreads();

    f32x4 oacc[4][2];
    #pragma unroll
    for (int qi = 0; qi < 4; ++qi) { oacc[qi][0] = vz; oacc[qi][1] = vz; }
    #pragma unroll
    for (int ks = 0; ks < 2; ++ks) {
        bf16x8 bv[2];
        #pragma unroll
        for (int dj = 0; dj < 2; ++dj)
            bv[dj] = *reinterpret_cast<const bf16x8*>(&uVt[(dj * 16 + l15) * 72 + ks * 32 + g4 * 8]);
        #pragma unroll
        for (int qi = 0; qi < 4; ++qi) {
            const bf16x8 ap = *reinterpret_cast<const bf16x8*>(&Ps[(qi * 16 + l15) * 72 + ks * 32 + g4 * 8]);
            #pragma unroll
            for (int dj = 0; dj < 2; ++dj)
                oacc[qi][dj] = __builtin_amdgcn_mfma_f32_16x16x32_bf16(ap, bv[dj], oacc[qi][dj], 0, 0, 0);
        }
    }
    #pragma unroll
    for (int qi = 0; qi < 4; ++qi) {
        #pragma unroll
        for (int r = 0; r < 4; ++r) {
            const int i = qi * 16 + g4 * 4 + r;
            if (i < NT_) {
                const size_t ob = (size_t)toks[i] * C_ + head * HD_ + l15;
                O[ob]      = __float2bfloat16(oacc[qi][0][r]);
                O[ob + 16] = __float2bfloat16(oacc[qi][1][r]);
            }
        }
    }
}

// ---------- launch ----------
extern "C" void kernel_launch(void* const* d_in, const int* in_sizes, int n_in,
                              void* d_out, int out_size, void* d_ws, size_t ws_size,
                              hipStream_t stream) {
    (void)out_size; (void)ws_size;
    char* ws = (char*)d_ws;
    const size_t WEIGHT_RESERVE = 12651520;
    bf16*  WC   = (bf16*)ws;
    int*   FLG  = (int*)(ws + WEIGHT_RESERVE);
    bf16*  TBL1 = (bf16*)(ws + WEIGHT_RESERVE + 1024);
    bf16*  TBL2 = (bf16*)(ws + WEIGHT_RESERVE + 1024 + 131072);
    bf16*  X    = (bf16*)(ws + WEIGHT_RESERVE + 656384);
    bf16*  XN   = X + (size_t)M_ * C_;
    char*  BIG  = (char*)(XN + (size_t)M_ * C_);

    size_t offs[27];
    size_t off = 0;
    for (int i = 1; i < n_in && i < 27; ++i) { offs[i] = off; off += (size_t)((in_sizes[i] + 7) & ~7); }
    auto wc = [&](int i) { return (const bf16*)(WC + offs[i]); };

    k_detect<<<1, 1, 0, stream>>>(d_in[1], FLG);
    {
        WArgs a;
        for (int i = 1; i < 27; ++i) {
            a.src[i - 1] = d_in[i];
            a.dst[i - 1] = WC + offs[i];
            a.n[i - 1]   = in_sizes[i];
        }
        k_convert_all<<<512, 256, 0, stream>>>(a, FLG);
    }
    k_mktbl<<<16, 256, 0, stream>>>(wc(7),  TBL1, 0);
    k_mktbl<<<64, 256, 0, stream>>>(wc(20), TBL2, 1);

    const dim3 gT(HW_ / 32, C_ / 32, B_);
    k_transpose_in<<<gT, 256, 0, stream>>>(d_in[0], X, FLG);

    bf16* QKV = (bf16*)BIG;
    bf16* ATT = (bf16*)(BIG + (size_t)M_ * 1536 * 2);
    bf16* HID = (bf16*)BIG;

    const int gQ = (1536 / 256) * (M_ / 256);   // 588  (qkv, 8-phase 256^2)
    const int gF = (2048 / 256) * (M_ / 256);   // 784  (fc1, 8-phase 256^2)
    const int gP = (512 / 128)  * (M_ / 256);   // 392  (proj, 256x128 NBUF=3)
    const int gO = (512 / 256)  * (M_ / 256);   // 196  (fc2, 8-phase 256^2)
    const int gL = M_ / 8;                      // 3136 (LN)
    const dim3 gA(B_ * 64 * NH_);

    // ================= branch 1: window attention =================
    k_layernorm<<<gL, 512, 0, stream>>>(X, wc(1), wc(2), XN);
    k_gemm8<bf16, bf16, false, false, false><<<gQ, 512, 0, stream>>>(
        XN, wc(3), wc(4), (const bf16*)nullptr, QKV, nullptr, 1536, C_);
    k_attn_mfma<0, false><<<gA, 64, 0, stream>>>(QKV, TBL1, ATT);
    k_gemm_mfma<bf16, bf16, false, true, false><<<gP, 512, 0, stream>>>(
        ATT, wc(5), wc(6), X, X, nullptr, C_, C_);
    // ================= MLP 1 =================
    k_layernorm<<<gL, 512, 0, stream>>>(X, wc(8), wc(9), XN);
    k_gemm8<bf16, bf16, true, false, false><<<gF, 512, 0, stream>>>(
        XN, wc(10), wc(11), (const bf16*)nullptr, HID, nullptr, 2048, C_);
    k_gemm8<bf16, bf16, false, true, false><<<gO, 512, 0, stream>>>(
        HID, wc(12), wc(13), X, X, nullptr, C_, 2048);
    // ============ branch 2: shifted window attention (residual = XN) ============
    k_layernorm<<<gL, 512, 0, stream>>>(X, wc(14), wc(15), XN);
    k_gemm8<bf16, bf16, false, false, false><<<gQ, 512, 0, stream>>>(
        XN, wc(16), wc(17), (const bf16*)nullptr, QKV, nullptr, 1536, C_);
    k_attn_mfma<3, true><<<gA, 64, 0, stream>>>(QKV, TBL2, ATT);
    k_gemm_mfma<bf16, bf16, false, true, false><<<gP, 512, 0, stream>>>(
        ATT, wc(18), wc(19), XN, X, nullptr, C_, C_);
    // ================= MLP 2 (final -> d_out, dtype per flag) =================
    k_layernorm<<<gL, 512, 0, stream>>>(X, wc(21), wc(22), XN);
    k_gemm8<bf16, bf16, true, false, false><<<gF, 512, 0, stream>>>(
        XN, wc(23), wc(24), (const bf16*)nullptr, HID, nullptr, 2048, C_);
    k_gemm8<bf16, float, false, true, true><<<gO, 512, 0, stream>>>(
        HID, wc(25), wc(26), X, (float*)d_out, FLG, C_, 2048);
}